// Round 1
// baseline (252.411 us; speedup 1.0000x reference)
//
#include <hip/hip_runtime.h>

#define ALPHA 0.2f
#define LDA 136   // LDS row stride in shorts (272 B: aligned, conflict-balanced)

typedef short bf16x8 __attribute__((ext_vector_type(8)));
typedef float f32x4  __attribute__((ext_vector_type(4)));

static __device__ __forceinline__ float bf2f(unsigned short u) {
    union { unsigned int i; float f; } v; v.i = ((unsigned int)u) << 16; return v.f;
}
static __device__ __forceinline__ unsigned short f2bf(float f) {
    union { float f; unsigned int i; } v; v.f = f;
    unsigned int x = v.i;
    return (unsigned short)((x + 0x7fffu + ((x >> 16) & 1u)) >> 16);  // RNE
}
// bf16 pair unpack: low short = <<16, high short = mask (1 VALU op each)
static __device__ __forceinline__ float bflo(int u) {
    union { unsigned int i; float f; } v; v.i = ((unsigned int)u) << 16; return v.f;
}
static __device__ __forceinline__ float bfhi(int u) {
    union { unsigned int i; float f; } v; v.i = ((unsigned int)u) & 0xffff0000u; return v.f;
}
// 8-channel FMA from one dwordx4 of bf16
static __device__ __forceinline__ void acc8(float* a, const int4 hv, const float w) {
    a[0] = fmaf(w, bflo(hv.x), a[0]); a[1] = fmaf(w, bfhi(hv.x), a[1]);
    a[2] = fmaf(w, bflo(hv.y), a[2]); a[3] = fmaf(w, bfhi(hv.y), a[3]);
    a[4] = fmaf(w, bflo(hv.z), a[4]); a[5] = fmaf(w, bfhi(hv.z), a[5]);
    a[6] = fmaf(w, bflo(hv.w), a[6]); a[7] = fmaf(w, bfhi(hv.w), a[7]);
}

// wT[c][k] = bf16(w[k][c]).  32 blocks x 128 thr (parallel, ~2 us).
__global__ __launch_bounds__(128)
void prep_wT_kernel(const float* __restrict__ w1, const float* __restrict__ w2,
                    unsigned short* __restrict__ wT1, unsigned short* __restrict__ wT2)
{
    const int b = blockIdx.x;
    const float* w = (b >> 4) ? w2 : w1;
    unsigned short* wT = (b >> 4) ? wT2 : wT1;
    const int k0 = (b & 15) * 8;
    const int c = threadIdx.x;          // 0..127

    ushort4 u0, u1;
    u0.x = f2bf(w[(k0 + 0) * 128 + c]); u0.y = f2bf(w[(k0 + 1) * 128 + c]);
    u0.z = f2bf(w[(k0 + 2) * 128 + c]); u0.w = f2bf(w[(k0 + 3) * 128 + c]);
    u1.x = f2bf(w[(k0 + 4) * 128 + c]); u1.y = f2bf(w[(k0 + 5) * 128 + c]);
    u1.z = f2bf(w[(k0 + 6) * 128 + c]); u1.w = f2bf(w[(k0 + 7) * 128 + c]);
    *(ushort4*)&wT[c * 128 + k0]     = u0;
    *(ushort4*)&wT[c * 128 + k0 + 4] = u1;
}

// Layer-1 GEMM + fused score dots (r10 structure, unchanged: 27 us).
__global__ __launch_bounds__(256, 4)
void gemm_score_mfma(const float* __restrict__ src,      // x, fp32
                     const unsigned short* __restrict__ wT,
                     const float* __restrict__ a_in,
                     const float* __restrict__ a_out,
                     unsigned short* __restrict__ hid,
                     float* __restrict__ s_in,
                     float* __restrict__ s_out,
                     int n)
{
    __shared__ short Bs[128 * LDA];   // 34816 B (epilogue reuses first half)
    __shared__ float aS[2][128];

    const int tid  = threadIdx.x;
    const int lane = tid & 63;
    const int wv   = tid >> 6;
    const int m    = lane & 15;
    const int q    = lane >> 4;
    const int rbase = blockIdx.x * 64;
    const int row   = rbase + wv * 16 + m;
    const bool rok  = (row < n);

    if (tid < 128) { aS[0][tid] = a_in[tid]; aS[1][tid] = a_out[tid]; }

    bf16x8 aF[4];
    {
        const float* p = &src[(size_t)row * 128 + q * 8];
        #pragma unroll
        for (int ks = 0; ks < 4; ks++) {
            if (rok) {
                float4 v0 = *(const float4*)(p + ks * 32);
                float4 v1 = *(const float4*)(p + ks * 32 + 4);
                bf16x8 a;
                a[0] = (short)f2bf(v0.x); a[1] = (short)f2bf(v0.y);
                a[2] = (short)f2bf(v0.z); a[3] = (short)f2bf(v0.w);
                a[4] = (short)f2bf(v1.x); a[5] = (short)f2bf(v1.y);
                a[6] = (short)f2bf(v1.z); a[7] = (short)f2bf(v1.w);
                aF[ks] = a;
            } else aF[ks] = (bf16x8){0,0,0,0,0,0,0,0};
        }
    }

    #pragma unroll
    for (int i = 0; i < 8; i++) {
        int e = tid + i * 256;
        int nr = e >> 4, j = (e & 15) * 8;
        int4 v = *(const int4*)&wT[nr * 128 + j];
        *(int4*)&Bs[nr * LDA + j] = v;
    }
    __syncthreads();

    f32x4 acc[8];
    #pragma unroll
    for (int t = 0; t < 8; t++) acc[t] = (f32x4){0.f, 0.f, 0.f, 0.f};

    const short* Bbase = &Bs[m * LDA + q * 8];
    #pragma unroll
    for (int ks = 0; ks < 4; ks++) {
        #pragma unroll
        for (int t = 0; t < 8; t++) {
            bf16x8 bF = *(const bf16x8*)(Bbase + t * 16 * LDA + ks * 32);
            acc[t] = __builtin_amdgcn_mfma_f32_16x16x32_bf16(aF[ks], bF, acc[t], 0, 0, 0);
        }
    }

    float pin[4] = {0.f, 0.f, 0.f, 0.f}, pout[4] = {0.f, 0.f, 0.f, 0.f};
    #pragma unroll
    for (int t = 0; t < 8; t++) {
        float ai = aS[0][t * 16 + m];
        float ao = aS[1][t * 16 + m];
        #pragma unroll
        for (int r = 0; r < 4; r++) {
            pin[r]  += acc[t][r] * ai;
            pout[r] += acc[t][r] * ao;
        }
    }
    #pragma unroll
    for (int msk = 8; msk >= 1; msk >>= 1) {
        #pragma unroll
        for (int r = 0; r < 4; r++) {
            pin[r]  += __shfl_xor(pin[r],  msk);
            pout[r] += __shfl_xor(pout[r], msk);
        }
    }
    if (m == 0) {
        #pragma unroll
        for (int r = 0; r < 4; r++) {
            int g = rbase + wv * 16 + q * 4 + r;
            if (g < n) { s_in[g] = pin[r]; s_out[g] = pout[r]; }
        }
    }

    __syncthreads();
    short* Es = Bs;
    #pragma unroll
    for (int t = 0; t < 8; t++)
        #pragma unroll
        for (int r = 0; r < 4; r++)
            Es[(wv * 16 + q * 4 + r) * LDA + t * 16 + m] = (short)f2bf(acc[t][r]);
    __syncthreads();
    #pragma unroll
    for (int i = 0; i < 4; i++) {
        int e = tid + i * 256;
        int r = e >> 4, j = (e & 15) * 8;
        int gr = rbase + r;
        if (gr < n) {
            int4 v = *(const int4*)&Es[r * LDA + j];
            *(int4*)&hid[(size_t)gr * 128 + j] = v;
        }
    }
}

// FUSED aggregate(layer1) + GEMM(layer2).
// Phase A reworked: wide gather. {dst, w_edge} pairs are staged in the first
// 128 B of each As row (zero extra LDS; overwritten by that row's own output,
// same-wave program order makes this safe). Gather: 16-lane group per node,
// dwordx4 loads (4 neighbor rows per wave-instruction) -> 64 load instrs/lane
// instead of 256, no readlane in the inner loop.
__global__ __launch_bounds__(256, 4)
void fused_agg_gemm(const unsigned short* __restrict__ hid1,
                    const float* __restrict__ s_in1,
                    const float* __restrict__ s_out1,
                    const int* __restrict__ dst,
                    const float* __restrict__ adj,
                    const float* __restrict__ bias1,
                    const unsigned short* __restrict__ wT2,
                    const float* __restrict__ a_in2,
                    const float* __restrict__ a_out2,
                    unsigned short* __restrict__ hid2,
                    float* __restrict__ s_in2,
                    float* __restrict__ s_out2,
                    int n)
{
    __shared__ short As[64 * LDA];    // pair table -> h1' tile; epilogue aliases it
    __shared__ short Bs[64 * LDA];    // HALF of wT2 at a time
    __shared__ float aS[2][128];

    const int tid  = threadIdx.x;
    const int lane = tid & 63;
    const int wv   = tid >> 6;
    const int rbase = blockIdx.x * 64;

    if (tid < 128) { aS[0][tid] = a_in2[tid]; aS[1][tid] = a_out2[tid]; }

    // stage Bs pass 1: wT2 rows 0..63 (cols 0..63 of W2)
    #pragma unroll
    for (int i = 0; i < 4; i++) {
        int e = tid + i * 256;                // 1024 int4 units
        int nr = e >> 4, j = (e & 15) * 8;
        int4 v = *(const int4*)&wT2[nr * 128 + j];
        *(int4*)&Bs[nr * LDA + j] = v;
    }

    // ---- Phase A1: softmax, 4 lanes/node ----
    const int jn  = lane >> 2;
    const int kq  = lane & 3;
    const int node = rbase + wv * 16 + jn;
    const bool nok = (node < n);

    int4   dk4 = make_int4(0, 0, 0, 0);
    float4 av4 = make_float4(0.f, 0.f, 0.f, 0.f);
    float  si  = 0.f;
    if (nok) {
        dk4 = *(const int4*)&dst[node * 16 + kq * 4];
        av4 = *(const float4*)&adj[node * 16 + kq * 4];
        si  = s_in1[node];
    }
    float e0 = si + s_out1[dk4.x], e1 = si + s_out1[dk4.y];
    float e2 = si + s_out1[dk4.z], e3 = si + s_out1[dk4.w];
    e0 = (e0 > 0.f) ? e0 : ALPHA * e0;  e1 = (e1 > 0.f) ? e1 : ALPHA * e1;
    e2 = (e2 > 0.f) ? e2 : ALPHA * e2;  e3 = (e3 > 0.f) ? e3 : ALPHA * e3;
    float mx = fmaxf(fmaxf(e0, e1), fmaxf(e2, e3));
    mx = fmaxf(mx, __shfl_xor(mx, 1));
    mx = fmaxf(mx, __shfl_xor(mx, 2));
    float p0 = __expf(e0 - mx), p1 = __expf(e1 - mx);
    float p2 = __expf(e2 - mx), p3 = __expf(e3 - mx);
    float sm = p0 + p1 + p2 + p3;
    sm += __shfl_xor(sm, 1);
    sm += __shfl_xor(sm, 2);
    const float inv = __frcp_rn(sm);

    // pair table {dk, wk} into bytes [0,128) of this node's As row
    {
        short* rowp = &As[(wv * 16 + jn) * LDA];
        int4 pa = make_int4(dk4.x, __float_as_int(av4.x * p0 * inv),
                            dk4.y, __float_as_int(av4.y * p1 * inv));
        int4 pb = make_int4(dk4.z, __float_as_int(av4.z * p2 * inv),
                            dk4.w, __float_as_int(av4.w * p3 * inv));
        *(int4*)(rowp + kq * 16)     = pa;   // pairs kq*4, kq*4+1
        *(int4*)(rowp + kq * 16 + 8) = pb;   // pairs kq*4+2, kq*4+3
    }

    // ---- Phase A2: gather, 16-lane group per node, dwordx4 loads ----
    const int m = lane & 15;
    const int q = lane >> 4;
    {
        const float4 bb0 = *(const float4*)&bias1[m * 8];
        const float4 bb1 = *(const float4*)&bias1[m * 8 + 4];
        #pragma unroll
        for (int jj = 0; jj < 4; jj++) {
            const int rloc = wv * 16 + jj * 4 + q;   // each (jj,q) owns one row
            const short* trow = &As[rloc * LDA];
            float acc[8] = {0.f, 0.f, 0.f, 0.f, 0.f, 0.f, 0.f, 0.f};
            #pragma unroll
            for (int k2 = 0; k2 < 8; k2++) {         // 2 neighbors per iter
                const int4 pp  = *(const int4*)(trow + k2 * 8);   // uniform bcast
                const int4 hv0 = *(const int4*)&hid1[((size_t)(unsigned)pp.x << 7) + (m << 3)];
                const int4 hv1 = *(const int4*)&hid1[((size_t)(unsigned)pp.z << 7) + (m << 3)];
                acc8(acc, hv0, __int_as_float(pp.y));
                acc8(acc, hv1, __int_as_float(pp.w));
            }
            const float r0 = fmaxf(acc[0] + bb0.x, 0.f);
            const float r1 = fmaxf(acc[1] + bb0.y, 0.f);
            const float r2 = fmaxf(acc[2] + bb0.z, 0.f);
            const float r3 = fmaxf(acc[3] + bb0.w, 0.f);
            const float r4 = fmaxf(acc[4] + bb1.x, 0.f);
            const float r5 = fmaxf(acc[5] + bb1.y, 0.f);
            const float r6 = fmaxf(acc[6] + bb1.z, 0.f);
            const float r7 = fmaxf(acc[7] + bb1.w, 0.f);
            int4 ov;
            ov.x = (int)f2bf(r0) | ((int)f2bf(r1) << 16);
            ov.y = (int)f2bf(r2) | ((int)f2bf(r3) << 16);
            ov.z = (int)f2bf(r4) | ((int)f2bf(r5) << 16);
            ov.w = (int)f2bf(r6) | ((int)f2bf(r7) << 16);
            *(int4*)&As[rloc * LDA + m * 8] = ov;    // overwrites own table: safe
        }
    }
    __syncthreads();

    // ---- Phase B: GEMM from As x Bs, two B passes ----
    // hoist A-fragments so the epilogue can alias As
    bf16x8 aF[4];
    {
        const short* Abase = &As[(wv * 16 + m) * LDA + q * 8];
        #pragma unroll
        for (int ks = 0; ks < 4; ks++)
            aF[ks] = *(const bf16x8*)(Abase + ks * 32);
    }

    f32x4 acc[8];
    #pragma unroll
    for (int t = 0; t < 8; t++) acc[t] = (f32x4){0.f, 0.f, 0.f, 0.f};

    const short* Bbase = &Bs[m * LDA + q * 8];
    #pragma unroll
    for (int ks = 0; ks < 4; ks++) {
        #pragma unroll
        for (int t = 0; t < 4; t++) {       // pass 1: W cols 0..63
            bf16x8 bF = *(const bf16x8*)(Bbase + t * 16 * LDA + ks * 32);
            acc[t] = __builtin_amdgcn_mfma_f32_16x16x32_bf16(aF[ks], bF, acc[t], 0, 0, 0);
        }
    }
    __syncthreads();
    #pragma unroll
    for (int i = 0; i < 4; i++) {           // restage: wT2 rows 64..127
        int e = tid + i * 256;
        int nr = e >> 4, j = (e & 15) * 8;
        int4 v = *(const int4*)&wT2[(64 + nr) * 128 + j];
        *(int4*)&Bs[nr * LDA + j] = v;
    }
    __syncthreads();
    #pragma unroll
    for (int ks = 0; ks < 4; ks++) {
        #pragma unroll
        for (int t = 4; t < 8; t++) {       // pass 2: W cols 64..127
            bf16x8 bF = *(const bf16x8*)(Bbase + (t - 4) * 16 * LDA + ks * 32);
            acc[t] = __builtin_amdgcn_mfma_f32_16x16x32_bf16(aF[ks], bF, acc[t], 0, 0, 0);
        }
    }

    // fused layer-2 score dots
    float pin[4] = {0.f, 0.f, 0.f, 0.f}, pout[4] = {0.f, 0.f, 0.f, 0.f};
    #pragma unroll
    for (int t = 0; t < 8; t++) {
        float ai = aS[0][t * 16 + m];
        float ao = aS[1][t * 16 + m];
        #pragma unroll
        for (int r = 0; r < 4; r++) {
            pin[r]  += acc[t][r] * ai;
            pout[r] += acc[t][r] * ao;
        }
    }
    #pragma unroll
    for (int msk = 8; msk >= 1; msk >>= 1) {
        #pragma unroll
        for (int r = 0; r < 4; r++) {
            pin[r]  += __shfl_xor(pin[r],  msk);
            pout[r] += __shfl_xor(pout[r], msk);
        }
    }
    if (m == 0) {
        #pragma unroll
        for (int r = 0; r < 4; r++) {
            int g = rbase + wv * 16 + q * 4 + r;
            if (g < n) { s_in2[g] = pin[r]; s_out2[g] = pout[r]; }
        }
    }

    __syncthreads();
    short* Es = As;                          // aF hoisted: As dead
    #pragma unroll
    for (int t = 0; t < 8; t++)
        #pragma unroll
        for (int r = 0; r < 4; r++)
            Es[(wv * 16 + q * 4 + r) * LDA + t * 16 + m] = (short)f2bf(acc[t][r]);
    __syncthreads();
    #pragma unroll
    for (int i = 0; i < 4; i++) {
        int e = tid + i * 256;
        int r = e >> 4, j = (e & 15) * 8;
        int gr = rbase + r;
        if (gr < n) {
            int4 v = *(const int4*)&Es[r * LDA + j];
            *(int4*)&hid2[(size_t)gr * 128 + j] = v;
        }
    }
}

// Final aggregate, restructured to the fused phase-A shape:
// 64 nodes/block, 16 nodes/wave, 4-lane softmax + LDS pair table,
// dwordx4 gather (4 rows per wave-instruction), float4 coalesced output.
__global__ __launch_bounds__(256, 4)
void gat_aggregate_final(const unsigned short* __restrict__ hid,
                         const float* __restrict__ s_in,
                         const float* __restrict__ s_out,
                         const int* __restrict__ dst,
                         const float* __restrict__ adj,
                         const float* __restrict__ bias,
                         float* __restrict__ out,
                         int n)
{
    __shared__ __align__(16) int2 tbl[64][18];   // 9216 B; stride 144 B (16-aligned,
                                                 // banks distinct across groups)
    const int tid  = threadIdx.x;
    const int lane = tid & 63;
    const int wv   = tid >> 6;
    const int rbase = blockIdx.x * 64;

    const int jn  = lane >> 2;
    const int kq  = lane & 3;
    const int node = rbase + wv * 16 + jn;
    const bool nok = (node < n);

    int4   dk4 = make_int4(0, 0, 0, 0);
    float4 av4 = make_float4(0.f, 0.f, 0.f, 0.f);
    float  si  = 0.f;
    if (nok) {
        dk4 = *(const int4*)&dst[node * 16 + kq * 4];
        av4 = *(const float4*)&adj[node * 16 + kq * 4];
        si  = s_in[node];
    }
    float e0 = si + s_out[dk4.x], e1 = si + s_out[dk4.y];
    float e2 = si + s_out[dk4.z], e3 = si + s_out[dk4.w];
    e0 = (e0 > 0.f) ? e0 : ALPHA * e0;  e1 = (e1 > 0.f) ? e1 : ALPHA * e1;
    e2 = (e2 > 0.f) ? e2 : ALPHA * e2;  e3 = (e3 > 0.f) ? e3 : ALPHA * e3;
    float mx = fmaxf(fmaxf(e0, e1), fmaxf(e2, e3));
    mx = fmaxf(mx, __shfl_xor(mx, 1));
    mx = fmaxf(mx, __shfl_xor(mx, 2));
    float p0 = __expf(e0 - mx), p1 = __expf(e1 - mx);
    float p2 = __expf(e2 - mx), p3 = __expf(e3 - mx);
    float sm = p0 + p1 + p2 + p3;
    sm += __shfl_xor(sm, 1);
    sm += __shfl_xor(sm, 2);
    const float inv = __frcp_rn(sm);

    {
        int4 pa = make_int4(dk4.x, __float_as_int(av4.x * p0 * inv),
                            dk4.y, __float_as_int(av4.y * p1 * inv));
        int4 pb = make_int4(dk4.z, __float_as_int(av4.z * p2 * inv),
                            dk4.w, __float_as_int(av4.w * p3 * inv));
        *(int4*)&tbl[wv * 16 + jn][kq * 4]     = pa;
        *(int4*)&tbl[wv * 16 + jn][kq * 4 + 2] = pb;
    }
    // table rows [wv*16, wv*16+16) written and read by the same wave: no barrier

    const int m = lane & 15;
    const int q = lane >> 4;
    const float4 bb0 = *(const float4*)&bias[m * 8];
    const float4 bb1 = *(const float4*)&bias[m * 8 + 4];

    #pragma unroll
    for (int jj = 0; jj < 4; jj++) {
        const int rl = wv * 16 + jj * 4 + q;
        const int nodeg = rbase + rl;
        float acc[8] = {0.f, 0.f, 0.f, 0.f, 0.f, 0.f, 0.f, 0.f};
        #pragma unroll
        for (int k2 = 0; k2 < 8; k2++) {
            const int4 pp  = *(const int4*)&tbl[rl][k2 * 2];      // uniform bcast
            const int4 hv0 = *(const int4*)&hid[((size_t)(unsigned)pp.x << 7) + (m << 3)];
            const int4 hv1 = *(const int4*)&hid[((size_t)(unsigned)pp.z << 7) + (m << 3)];
            acc8(acc, hv0, __int_as_float(pp.y));
            acc8(acc, hv1, __int_as_float(pp.w));
        }
        if (nodeg < n) {
            float4 o0, o1;
            o0.x = fmaxf(acc[0] + bb0.x, 0.f);
            o0.y = fmaxf(acc[1] + bb0.y, 0.f);
            o0.z = fmaxf(acc[2] + bb0.z, 0.f);
            o0.w = fmaxf(acc[3] + bb0.w, 0.f);
            o1.x = fmaxf(acc[4] + bb1.x, 0.f);
            o1.y = fmaxf(acc[5] + bb1.y, 0.f);
            o1.z = fmaxf(acc[6] + bb1.z, 0.f);
            o1.w = fmaxf(acc[7] + bb1.w, 0.f);
            float* op = &out[(size_t)nodeg * 128 + m * 8];
            *(float4*)op       = o0;
            *(float4*)(op + 4) = o1;
        }
    }
}

extern "C" void kernel_launch(void* const* d_in, const int* in_sizes, int n_in,
                              void* d_out, int out_size, void* d_ws, size_t ws_size,
                              hipStream_t stream)
{
    const float* x      = (const float*)d_in[0];
    const int*   dst    = (const int*)d_in[1];
    const float* adj    = (const float*)d_in[2];
    const float* w1     = (const float*)d_in[3];
    const float* a_in1  = (const float*)d_in[4];
    const float* a_out1 = (const float*)d_in[5];
    const float* b1     = (const float*)d_in[6];
    const float* w2     = (const float*)d_in[7];
    const float* a_in2  = (const float*)d_in[8];
    const float* a_out2 = (const float*)d_in[9];
    const float* b2     = (const float*)d_in[10];

    const int N = in_sizes[0] / 128;               // 100000

    // ws: hid2 bf16 (25.6MB) | s_in1 | s_out1 | s_in2 | s_out2 | wT1 | wT2
    unsigned short* hid2  = (unsigned short*)d_ws;
    float*          s_in1 = (float*)(hid2 + (size_t)N * 128);
    float*          s_out1= s_in1 + N;
    float*          s_in2 = s_out1 + N;
    float*          s_out2= s_in2 + N;
    unsigned short* wT1   = (unsigned short*)(s_out2 + N);
    unsigned short* wT2   = wT1 + 128 * 128;
    // hid_L1 (bf16) lives in the upper half of the fp32 d_out;
    // the final aggregate overwrites d_out only after hid_L1 is dead.
    unsigned short* hid1  = (unsigned short*)d_out + out_size;

    dim3 blk(256);
    dim3 ggrid((N + 63) / 64);                     // 1563

    prep_wT_kernel<<<32, 128, 0, stream>>>(w1, w2, wT1, wT2);

    gemm_score_mfma<<<ggrid, blk, 0, stream>>>(x, wT1, a_in1, a_out1,
                                               hid1, s_in1, s_out1, N);
    fused_agg_gemm<<<ggrid, blk, 0, stream>>>(hid1, s_in1, s_out1, dst, adj, b1,
                                              wT2, a_in2, a_out2,
                                              hid2, s_in2, s_out2, N);
    gat_aggregate_final<<<ggrid, blk, 0, stream>>>(hid2, s_in2, s_out2, dst, adj,
                                                   b2, (float*)d_out, N);
}